// Round 15
// baseline (1746.129 us; speedup 1.0000x reference)
//
#include <hip/hip_runtime.h>
#include <cmath>

// DHT: out[n,c,a,r] = sum over px (x,y) of feat[n,c,y,x],
//   r = rint((x-128)*cos(a deg) + (y-128)*sin(a deg)) + 361  (r in [180,542])
// feat[4,128,256,256] f32 -> out[4,128,180,723] f32.
//
// Locked-in findings:
//  R1-R4 (~31ms): LDS f32 atomicAdd serializes ~per-lane -> never on hot path.
//  R5 (2.69ms): wave-private rows + plain program-ordered DS RMW, race-free
//    when concurrent lanes' bins provably distinct.
//  R6: image re-reads at >1 block/CU -> HBM-bound. R10: exec-masked DS RMW
//    poison. R11: occupancy not binding.
//  R7 (1.85ms): register-persistent px across ALL angles.
//  R12 (1.54ms) / R14 (1.55ms): b64 pair-RMW. Conflict count INVARIANT at
//    ~2.8e8 across lane strides, 3 swizzles, angle interleave, widths ->
//    QUASI-RANDOM RESIDUE TAX: rint-of-irrational-stride bins give a
//    64-balls/32-banks pattern; ~3 extra cyc PER DS INSTRUCTION, immune to
//    bijective remaps. (R12: 2.96/instr; R11: 2.78; R13: 2.6.)
//  R15: the tax is per-INSTRUCTION -> halve instructions: b128 RMW packing
//    4 IMAGES per float4 row (bins image-independent). Port bytes same,
//    DS instr 94.4e6 -> 47.2e6, walk VALU shared by 4 imgs.

#define NA 180
#define NR 723
#define HW 65536
#define NC 512
#define ROW_W 368       // bins rl = r-RBASE in [4,366]
#define ROW_PAD 368     // float4 elements per wave-copy
#define RBASE 176
#define NWIN 32         // 8-px windows along the scan axis

__device__ __forceinline__ bool is_phase2(int a) { return a >= 46 && a <= 134; }

// ---------------------------------------------------------------------------
// win[a][w][fast] u32 = base bin at scan=8w (bits 0..15), step bits 16..22.
// Phase-1 (a in [0,45]u[135,179]): fast=x, scan=y (step coef sin(a)>=0).
// Phase-2 (a in [46,134]):         fast=y, scan=x (step coef cos(a), sign
// flips at a=90). fp64 non-fused mul/add + rint bit-matches np.round
// (validated R1-R14: absmax 0.25 = f32 sum-order noise only).
// ---------------------------------------------------------------------------
__global__ __launch_bounds__(256) void dht_win(unsigned int* __restrict__ win) {
    const int lane = threadIdx.x;
    const int w = blockIdx.x;
    const int a = blockIdx.y;
    const double theta = (double)a * (M_PI / 180.0);
    const double c = cos(theta), s = sin(theta);
    const bool p2 = is_phase2(a);
    int prev = 0;
    unsigned int word = 0;
    #pragma unroll
    for (int i = 0; i < 8; ++i) {
        const int k = w * 8 + i;
        const int x = p2 ? k : lane;
        const int y = p2 ? lane : k;
        const double rho = __dadd_rn(__dmul_rn((double)(x - 128), c),
                                     __dmul_rn((double)(y - 128), s));
        int r = (int)rint(rho) + 361;
        r = min(max(r, 0), NR - 1);
        if (i == 0) word = (unsigned int)r;
        else if (r != prev) word |= (1u << (15 + i));
        prev = r;
    }
    win[((size_t)a * NWIN + w) * 256 + lane] = word;
}

__global__ __launch_bounds__(256) void zero_out(float4* __restrict__ o, int n4) {
    const int i = blockIdx.x * 256 + threadIdx.x;
    if (i < n4) o[i] = make_float4(0.f, 0.f, 0.f, 0.f);
}

// Branchless 8(scan) x 2(col) x 4(img) walk, b128 RMW. Concurrent lanes
// (fixed j) sit 2 columns apart -> bin spacing 2|coef| >= 1.414 -> distinct
// addresses -> race-free (program-ordered same-wave DS). Dense RMW stream.
template <int SGN>
__device__ __forceinline__ void walk4(const uint2 u, const float4 (&px)[8][2],
                                      float4* __restrict__ rp) {
    #pragma unroll
    for (int j = 0; j < 2; ++j) {
        const unsigned int wrd = j ? u.y : u.x;
        int bin = (int)(wrd & 0xffffu) - RBASE;
        #pragma unroll
        for (int k = 0; k < 8; ++k) {
            if (k) bin += SGN * (int)((wrd >> (15 + k)) & 1u);
            float4 v = rp[bin];
            v.x += px[k][j].x; v.y += px[k][j].y;
            v.z += px[k][j].z; v.w += px[k][j].w;
            rp[bin] = v;
        }
    }
}

// ---------------------------------------------------------------------------
// Block = (image-quad, phase, scan-quarter). 1024 thr = 16 waves.
// Wave wv: scan window ww = wv>>1 (8 lines at k0 = 64*z + 8*ww), fast half
// fh = wv&1; lane owns fast cols {128fh+2l, 128fh+2l+1}. px float4[8][2]
// (64 VGPR) loaded ONCE, reused across all angles of the phase.
// rows[16 waves][ROW_PAD] float4 = 94 KB -> 1 block/CU. Flush every angle.
// ---------------------------------------------------------------------------
__global__ __launch_bounds__(1024, 4) void dht_main(const float* __restrict__ feat,
                                                    const unsigned int* __restrict__ win,
                                                    float* __restrict__ out) {
    __shared__ float4 rows[16 * ROW_PAD];   // 94.2 KB
    const int t = threadIdx.x;
    const int wv = t >> 6;
    const int l = t & 63;
    const int quad = blockIdx.x;
    const int phase = blockIdx.y;
    const int z = blockIdx.z;           // scan quarter
    const int ww = wv >> 1;             // window within quarter, 0..7
    const int fh = wv & 1;              // fast half
    const int w = 8 * z + ww;           // global window index 0..31
    const int k0 = 8 * w;               // scan offset (= 64z + 8ww)
    const int fj0 = 128 * fh + 2 * l;   // first fast col of this lane

    const float* __restrict__ f0 = feat + (size_t)(4 * quad + 0) * HW;
    const float* __restrict__ f1 = feat + (size_t)(4 * quad + 1) * HW;
    const float* __restrict__ f2 = feat + (size_t)(4 * quad + 2) * HW;
    const float* __restrict__ f3 = feat + (size_t)(4 * quad + 3) * HW;
    float* __restrict__ o0 = out + (size_t)(4 * quad + 0) * (NA * NR);
    float* __restrict__ o1 = out + (size_t)(4 * quad + 1) * (NA * NR);
    float* __restrict__ o2 = out + (size_t)(4 * quad + 2) * (NA * NR);
    float* __restrict__ o3 = out + (size_t)(4 * quad + 3) * (NA * NR);

    // ---- load persistent px tile: 8 scan x 2 fast x 4 img ----
    float4 px[8][2];
    if (phase == 0) {
        // scan=y: row y=k0+k; fast=x at {fj0, fj0+1} (float2 per img, coalesced)
        #pragma unroll
        for (int k = 0; k < 8; ++k) {
            const float2 a0 = *(const float2*)(f0 + ((k0 + k) << 8) + fj0);
            const float2 a1 = *(const float2*)(f1 + ((k0 + k) << 8) + fj0);
            const float2 a2 = *(const float2*)(f2 + ((k0 + k) << 8) + fj0);
            const float2 a3 = *(const float2*)(f3 + ((k0 + k) << 8) + fj0);
            px[k][0] = make_float4(a0.x, a1.x, a2.x, a3.x);
            px[k][1] = make_float4(a0.y, a1.y, a2.y, a3.y);
        }
    } else {
        // scan=x: fast=y rows {fj0, fj0+1}; cols x=k0..k0+7 (2 float4 per row/img)
        #pragma unroll
        for (int j = 0; j < 2; ++j) {
            const int fr = fj0 + j;
            const float4 qa = *(const float4*)(f0 + (fr << 8) + k0);
            const float4 qb = *(const float4*)(f0 + (fr << 8) + k0 + 4);
            const float4 ra = *(const float4*)(f1 + (fr << 8) + k0);
            const float4 rb = *(const float4*)(f1 + (fr << 8) + k0 + 4);
            const float4 sa = *(const float4*)(f2 + (fr << 8) + k0);
            const float4 sb = *(const float4*)(f2 + (fr << 8) + k0 + 4);
            const float4 ta = *(const float4*)(f3 + (fr << 8) + k0);
            const float4 tb = *(const float4*)(f3 + (fr << 8) + k0 + 4);
            px[0][j] = make_float4(qa.x, ra.x, sa.x, ta.x);
            px[1][j] = make_float4(qa.y, ra.y, sa.y, ta.y);
            px[2][j] = make_float4(qa.z, ra.z, sa.z, ta.z);
            px[3][j] = make_float4(qa.w, ra.w, sa.w, ta.w);
            px[4][j] = make_float4(qb.x, rb.x, sb.x, tb.x);
            px[5][j] = make_float4(qb.y, rb.y, sb.y, tb.y);
            px[6][j] = make_float4(qb.z, rb.z, sb.z, tb.z);
            px[7][j] = make_float4(qb.w, rb.w, sb.w, tb.w);
        }
    }

    const int nAng = phase ? 89 : 91;
    for (int aidx = 0; aidx < nAng; ++aidx) {
        #pragma unroll 2
        for (int i = t; i < 16 * ROW_PAD; i += 1024)
            rows[i] = make_float4(0.f, 0.f, 0.f, 0.f);
        __syncthreads();

        const int a = phase ? (46 + aidx) : (aidx <= 45 ? aidx : aidx + 89);
        const uint2 u = *(const uint2*)(win + ((size_t)a * NWIN + w) * 256 + fj0);
        float4* __restrict__ rp = rows + wv * ROW_PAD;
        if (phase && a > 90) walk4<-1>(u, px, rp);
        else                 walk4<+1>(u, px, rp);
        __syncthreads();

        // flush: thread t < 368 sums the 16 wave copies of bin t (dense b128
        // reads) and issues 4 contiguous global atomic adds (one per image).
        // 4 commutative contributions per out element (the 4 scan-quarters).
        if (t < ROW_W) {
            float4 s = make_float4(0.f, 0.f, 0.f, 0.f);
            #pragma unroll
            for (int c2 = 0; c2 < 16; ++c2) {
                const float4 v = rows[c2 * ROW_PAD + t];
                s.x += v.x; s.y += v.y; s.z += v.z; s.w += v.w;
            }
            const size_t o = (size_t)a * NR + (RBASE + t);
            unsafeAtomicAdd(o0 + o, s.x);
            unsafeAtomicAdd(o1 + o, s.y);
            unsafeAtomicAdd(o2 + o, s.z);
            unsafeAtomicAdd(o3 + o, s.w);
        }
        __syncthreads();
    }
}

extern "C" void kernel_launch(void* const* d_in, const int* in_sizes, int n_in,
                              void* d_out, int out_size, void* d_ws, size_t ws_size,
                              hipStream_t stream) {
    const float* feat = (const float*)d_in[0];
    float* out = (float*)d_out;
    unsigned int* win = (unsigned int*)d_ws;

    const size_t win_bytes = (size_t)NA * NWIN * 256 * sizeof(unsigned int); // 5.9MB
    if (ws_size < win_bytes) return;

    const int n4 = out_size / 4;   // out_size = 512*180*723, divisible by 4
    hipLaunchKernelGGL(zero_out, dim3((n4 + 255) / 256), dim3(256), 0, stream,
                       (float4*)out, n4);
    hipLaunchKernelGGL(dht_win, dim3(NWIN, NA), dim3(256), 0, stream, win);
    hipLaunchKernelGGL(dht_main, dim3(NC / 4, 2, 4), dim3(1024), 0, stream,
                       feat, win, out);
}

// Round 16
// 1672.037 us; speedup vs baseline: 1.0443x; 1.0443x over previous
//
#include <hip/hip_runtime.h>
#include <cmath>

// DHT: out[n,c,a,r] = sum over px (x,y) of feat[n,c,y,x],
//   r = rint((x-128)*cos(a deg) + (y-128)*sin(a deg)) + 361  (r in [180,542])
// feat[4,128,256,256] f32 -> out[4,128,180,723] f32.
//
// Locked-in findings:
//  R1-R4 (~31ms): LDS f32 atomicAdd serializes ~per-lane -> never on hot path.
//  R5 (2.69ms): wave-private rows + plain program-ordered DS RMW, race-free
//    when concurrent lanes' bins provably distinct.
//  R6: image re-reads at >1 block/CU -> HBM-bound. R10: exec-masked DS RMW
//    poison. R7 (1.85ms): register-persistent px across ALL angles.
//  R12 (1.50ms, BEST): b64 pair-RMW, stride-2 lane columns, no swizzle.
//  R8/R9/R13/R14/R15: SQ_LDS_BANK_CONFLICT ~2.8e8 invariant under lane
//    strides, 3 swizzles, angle interleave, AND instruction width (b32/b64/
//    b128) -> the counter tracks PORT BYTES (extra cycles of multi-cycle
//    wave-wide DS ops). 48.3 GB RMW traffic ~= 600-770us irreducible floor
//    for the scatter structure. Lane-address engineering is DEAD.
//  R16: occupancy discriminator. Same structure at 512-thr blocks, 4 scan-
//    quarters, 47KB rows -> 3 blocks/CU = 6 waves/SIMD (was 4). If the
//    ~450us unattributed gap is RMW-latency stalls -> 1200-1350us. If
//    unchanged -> port floor reached, roofline next.

#define NA 180
#define NR 723
#define HW 65536
#define NC 512
#define CH 2            // angles per LDS chunk
#define ROW_W 368       // bins rl = r-RBASE in [4,366]
#define ROW_PAD 368
#define RBASE 176
#define NWIN 32         // 8-px windows along the scan axis
#define NCP 8           // wave copies per block (8 waves)

__device__ __forceinline__ bool is_phase2(int a) { return a >= 46 && a <= 134; }

// ---------------------------------------------------------------------------
// win[a][w][fast] u32 = base bin at scan=8w (bits 0..15), step bits 16..22.
// Phase-1 (a in [0,45]u[135,179]): fast=x, scan=y (step coef sin(a)>=0).
// Phase-2 (a in [46,134]):         fast=y, scan=x (step coef cos(a), sign
// flips at a=90). fp64 non-fused mul/add + rint bit-matches np.round
// (validated R1-R15: absmax 0.25 = f32 sum-order noise only).
// ---------------------------------------------------------------------------
__global__ __launch_bounds__(256) void dht_win(unsigned int* __restrict__ win) {
    const int lane = threadIdx.x;
    const int w = blockIdx.x;
    const int a = blockIdx.y;
    const double theta = (double)a * (M_PI / 180.0);
    const double c = cos(theta), s = sin(theta);
    const bool p2 = is_phase2(a);
    int prev = 0;
    unsigned int word = 0;
    #pragma unroll
    for (int i = 0; i < 8; ++i) {
        const int k = w * 8 + i;
        const int x = p2 ? k : lane;
        const int y = p2 ? lane : k;
        const double rho = __dadd_rn(__dmul_rn((double)(x - 128), c),
                                     __dmul_rn((double)(y - 128), s));
        int r = (int)rint(rho) + 361;
        r = min(max(r, 0), NR - 1);
        if (i == 0) word = (unsigned int)r;
        else if (r != prev) word |= (1u << (15 + i));
        prev = r;
    }
    win[((size_t)a * NWIN + w) * 256 + lane] = word;
}

__global__ __launch_bounds__(256) void zero_out(float4* __restrict__ o, int n4) {
    const int i = blockIdx.x * 256 + threadIdx.x;
    if (i < n4) o[i] = make_float4(0.f, 0.f, 0.f, 0.f);
}

// Branchless 8(scan) x 4(col) x 2(img) walk, b64 RMW, unswizzled (R12 form).
// Concurrent lanes (fixed j) sit 2 columns apart -> bin spacing
// 2|coef| >= 1.414 -> distinct addresses -> race-free (program-ordered
// same-wave DS). Dense unconditional RMW stream.
template <int SGN>
__device__ __forceinline__ void walk2(const uint4 wq, const float2 (&px)[8][4],
                                      float2* __restrict__ rp) {
    #pragma unroll
    for (int j = 0; j < 4; ++j) {
        const unsigned int wrd = (&wq.x)[j];
        int bin = (int)(wrd & 0xffffu) - RBASE;
        #pragma unroll
        for (int k = 0; k < 8; ++k) {
            if (k) bin += SGN * (int)((wrd >> (15 + k)) & 1u);
            float2 v = rp[bin];
            v.x += px[k][j].x;
            v.y += px[k][j].y;
            rp[bin] = v;
        }
    }
}

// ---------------------------------------------------------------------------
// Block = (image-pair, phase, scan-QUARTER). 512 thr = 8 waves; wave wv owns
// scan window w = 8z+wv (8 scan lines); lane owns fast columns
// {2l, 2l+1, 2l+128, 2l+129} (j = 0..3). px float2[8][4] loaded ONCE,
// reused across all angles of the phase.
// rows[8 waves][CH][ROW_PAD] float2 = 47.1 KB -> 3 blocks/CU = 6 waves/SIMD.
// ---------------------------------------------------------------------------
__global__ __launch_bounds__(512, 6) void dht_main(const float* __restrict__ feat,
                                                   const unsigned int* __restrict__ win,
                                                   float* __restrict__ out) {
    __shared__ float2 rows[NCP * CH * ROW_PAD];   // 47.1 KB
    const int t = threadIdx.x;
    const int wv = t >> 6;              // 0..7
    const int l = t & 63;
    const int pair = blockIdx.x;
    const int phase = blockIdx.y;
    const int z = blockIdx.z;           // scan quarter 0..3
    const int w = 8 * z + wv;           // scan window 0..31
    const int k0 = 8 * w;               // scan offset
    const float* __restrict__ f0 = feat + (size_t)(2 * pair) * HW;
    const float* __restrict__ f1 = feat + (size_t)(2 * pair + 1) * HW;
    float* __restrict__ o0 = out + (size_t)(2 * pair) * (NA * NR);
    float* __restrict__ o1 = out + (size_t)(2 * pair + 1) * (NA * NR);

    // fast-axis indices owned by this lane (j = 0..3)
    const int fj0 = 2 * l;        // and fj0+1
    const int fj2 = 2 * l + 128;  // and fj2+1

    // ---- load persistent px tile: 8 scan x 4 fast x 2 img ----
    float2 px[8][4];
    if (phase == 0) {
        // scan=y: row y=k0+k; fast=x at {2l,2l+1} and {2l+128,2l+129}
        #pragma unroll
        for (int k = 0; k < 8; ++k) {
            const float2 a0 = *(const float2*)(f0 + ((k0 + k) << 8) + fj0);
            const float2 a1 = *(const float2*)(f0 + ((k0 + k) << 8) + fj2);
            const float2 b0 = *(const float2*)(f1 + ((k0 + k) << 8) + fj0);
            const float2 b1 = *(const float2*)(f1 + ((k0 + k) << 8) + fj2);
            px[k][0] = make_float2(a0.x, b0.x); px[k][1] = make_float2(a0.y, b0.y);
            px[k][2] = make_float2(a1.x, b1.x); px[k][3] = make_float2(a1.y, b1.y);
        }
    } else {
        // scan=x: fast=y rows {2l,2l+1,2l+128,2l+129}; cols x=k0..k0+7
        #pragma unroll
        for (int j = 0; j < 4; ++j) {
            const int fr = (j < 2) ? (fj0 + j) : (fj2 + (j - 2));
            const float4 q0 = *(const float4*)(f0 + (fr << 8) + k0);
            const float4 q1 = *(const float4*)(f0 + (fr << 8) + k0 + 4);
            const float4 r0 = *(const float4*)(f1 + (fr << 8) + k0);
            const float4 r1 = *(const float4*)(f1 + (fr << 8) + k0 + 4);
            px[0][j] = make_float2(q0.x, r0.x); px[1][j] = make_float2(q0.y, r0.y);
            px[2][j] = make_float2(q0.z, r0.z); px[3][j] = make_float2(q0.w, r0.w);
            px[4][j] = make_float2(q1.x, r1.x); px[5][j] = make_float2(q1.y, r1.y);
            px[6][j] = make_float2(q1.z, r1.z); px[7][j] = make_float2(q1.w, r1.w);
        }
    }

    const int nAng = phase ? 89 : 91;
    for (int cb = 0; cb < nAng; cb += CH) {
        const int cn = min(CH, nAng - cb);
        for (int i = t; i < NCP * CH * ROW_PAD; i += 512)
            rows[i] = make_float2(0.f, 0.f);
        __syncthreads();

        for (int ai = 0; ai < cn; ++ai) {
            const int aidx = cb + ai;
            const int a = phase ? (46 + aidx) : (aidx <= 45 ? aidx : aidx + 89);
            const unsigned int* wrow = win + ((size_t)a * NWIN + w) * 256;
            const uint2 u0 = *(const uint2*)(wrow + fj0);   // cols 2l, 2l+1
            const uint2 u1 = *(const uint2*)(wrow + fj2);   // cols 2l+128, 2l+129
            uint4 wq; wq.x = u0.x; wq.y = u0.y; wq.z = u1.x; wq.w = u1.y;
            float2* __restrict__ rp = rows + (wv * CH + ai) * ROW_PAD;
            if (phase && a > 90) walk2<-1>(wq, px, rp);
            else                 walk2<+1>(wq, px, rp);
        }
        __syncthreads();

        // flush: lanes iterate rl contiguously -> contiguous global atomics.
        // 4 commutative atomic contributions per out element (4 quarters).
        for (int i = t; i < cn * ROW_W; i += 512) {
            const int al = i / ROW_W;
            const int rl = i - al * ROW_W;
            float sx = 0.f, sy = 0.f;
            #pragma unroll
            for (int c2 = 0; c2 < NCP; ++c2) {
                const float2 v = rows[(c2 * CH + al) * ROW_PAD + rl];
                sx += v.x; sy += v.y;
            }
            const int aidx = cb + al;
            const int a = phase ? (46 + aidx) : (aidx <= 45 ? aidx : aidx + 89);
            const size_t o = (size_t)a * NR + (RBASE + rl);
            unsafeAtomicAdd(o0 + o, sx);
            unsafeAtomicAdd(o1 + o, sy);
        }
        __syncthreads();
    }
}

extern "C" void kernel_launch(void* const* d_in, const int* in_sizes, int n_in,
                              void* d_out, int out_size, void* d_ws, size_t ws_size,
                              hipStream_t stream) {
    const float* feat = (const float*)d_in[0];
    float* out = (float*)d_out;
    unsigned int* win = (unsigned int*)d_ws;

    const size_t win_bytes = (size_t)NA * NWIN * 256 * sizeof(unsigned int); // 5.9MB
    if (ws_size < win_bytes) return;

    const int n4 = out_size / 4;   // out_size = 512*180*723, divisible by 4
    hipLaunchKernelGGL(zero_out, dim3((n4 + 255) / 256), dim3(256), 0, stream,
                       (float4*)out, n4);
    hipLaunchKernelGGL(dht_win, dim3(NWIN, NA), dim3(256), 0, stream, win);
    hipLaunchKernelGGL(dht_main, dim3(NC / 2, 2, 4), dim3(512), 0, stream,
                       feat, win, out);
}

// Round 17
// 857.113 us; speedup vs baseline: 2.0372x; 1.9508x over previous
//
#include <hip/hip_runtime.h>
#include <hip/hip_fp16.h>
#include <cmath>

// DHT: out[n,c,a,r] = sum over px (x,y) of feat[n,c,y,x],
//   r = rint((x-128)*cos(a deg) + (y-128)*sin(a deg)) + 361  (r in [180,542])
// feat[4,128,256,256] f32 -> out[4,128,180,723] f32.
//
// Locked-in findings:
//  R1-R4 (~31ms): LDS f32 atomicAdd serializes ~per-lane -> never on hot path.
//  R5: wave-private rows + plain program-ordered DS RMW, race-free when
//    concurrent lanes' bins provably distinct. R10: exec-masked DS poison.
//  R7: register-persistent px across ALL angles. R12 (1.50ms, BEST f32).
//  R8/R9/R13/R14/R15: SQ_LDS_BANK_CONFLICT invariant under every address
//    remap and instruction width -> it's a PORT-BYTE occupancy tax
//    (~byte-proportional), not fixable conflicts.
//  R16: occupancy 48->67% bought nothing (LDS port is per-CU); quartering's
//    4x global-atomic traffic cost ~250us. Halves (2 contribs/out) only.
//  R17: halve RMW bytes/image-visit: LDS accumulators in f16, 4 IMAGES per
//    b64 RMW via v_pk_add_f16 (2 VALU/visit, same as R12). Error budget:
//    ~5.6 f16 adds per wave-copy bin + f32 copy-sum + f32->f16 px quant
//    => absmax ~0.3-0.6 << 1.91 threshold. Flush converts f32 before the
//    2 commutative global atomics -> deterministic.

#define NA 180
#define NR 723
#define HW 65536
#define NC 512
#define CH 2            // angles per LDS chunk
#define ROW_W 368       // bins rl = r-RBASE in [4,366]
#define ROW_PAD 368
#define RBASE 176
#define NWIN 32         // 8-px windows along the scan axis

__device__ __forceinline__ bool is_phase2(int a) { return a >= 46 && a <= 134; }

// 4 images packed per bin: .a = {img0,img1}, .b = {img2,img3}
struct __align__(8) h4 { __half2 a, b; };

// ---------------------------------------------------------------------------
// win[a][w][fast] u32 = base bin at scan=8w (bits 0..15), step bits 16..22.
// Phase-1 (a in [0,45]u[135,179]): fast=x, scan=y (step coef sin(a)>=0).
// Phase-2 (a in [46,134]):         fast=y, scan=x (step coef cos(a), sign
// flips at a=90). fp64 non-fused mul/add + rint bit-matches np.round
// (validated R1-R16: absmax 0.25 = f32 sum-order noise only).
// ---------------------------------------------------------------------------
__global__ __launch_bounds__(256) void dht_win(unsigned int* __restrict__ win) {
    const int lane = threadIdx.x;
    const int w = blockIdx.x;
    const int a = blockIdx.y;
    const double theta = (double)a * (M_PI / 180.0);
    const double c = cos(theta), s = sin(theta);
    const bool p2 = is_phase2(a);
    int prev = 0;
    unsigned int word = 0;
    #pragma unroll
    for (int i = 0; i < 8; ++i) {
        const int k = w * 8 + i;
        const int x = p2 ? k : lane;
        const int y = p2 ? lane : k;
        const double rho = __dadd_rn(__dmul_rn((double)(x - 128), c),
                                     __dmul_rn((double)(y - 128), s));
        int r = (int)rint(rho) + 361;
        r = min(max(r, 0), NR - 1);
        if (i == 0) word = (unsigned int)r;
        else if (r != prev) word |= (1u << (15 + i));
        prev = r;
    }
    win[((size_t)a * NWIN + w) * 256 + lane] = word;
}

__global__ __launch_bounds__(256) void zero_out(float4* __restrict__ o, int n4) {
    const int i = blockIdx.x * 256 + threadIdx.x;
    if (i < n4) o[i] = make_float4(0.f, 0.f, 0.f, 0.f);
}

// Branchless 8(scan) x 4(col) x 4(img,f16) walk, b64 RMW. Concurrent lanes
// (fixed j) sit 2 columns apart -> bin spacing 2|coef| >= 1.414 -> distinct
// addresses -> race-free (program-ordered same-wave DS). Dense RMW stream.
template <int SGN>
__device__ __forceinline__ void walk4h(const uint4 wq,
                                       const __half2 (&pxA)[8][4],
                                       const __half2 (&pxB)[8][4],
                                       h4* __restrict__ rp) {
    #pragma unroll
    for (int j = 0; j < 4; ++j) {
        const unsigned int wrd = (&wq.x)[j];
        int bin = (int)(wrd & 0xffffu) - RBASE;
        #pragma unroll
        for (int k = 0; k < 8; ++k) {
            if (k) bin += SGN * (int)((wrd >> (15 + k)) & 1u);
            h4 v = rp[bin];
            v.a = __hadd2(v.a, pxA[k][j]);   // v_pk_add_f16: img0,img1
            v.b = __hadd2(v.b, pxB[k][j]);   // img2,img3
            rp[bin] = v;
        }
    }
}

// ---------------------------------------------------------------------------
// Block = (image-quad, phase, scan-half). 1024 thr = 16 waves; wave wv owns
// scan window w = 16h+wv (8 scan lines); lane owns fast columns
// {2l, 2l+1, 2l+128, 2l+129} (j = 0..3). px as __half2 pairs (64 VGPR),
// loaded+converted ONCE, reused across all angles of the phase.
// rows[16 waves][CH][ROW_PAD] h4 = 94 KB -> 1 block/CU.
// ---------------------------------------------------------------------------
__global__ __launch_bounds__(1024, 4) void dht_main(const float* __restrict__ feat,
                                                    const unsigned int* __restrict__ win,
                                                    float* __restrict__ out) {
    __shared__ h4 rows[16 * CH * ROW_PAD];   // 94.2 KB
    const int t = threadIdx.x;
    const int wv = t >> 6;
    const int l = t & 63;
    const int quad = blockIdx.x;
    const int phase = blockIdx.y;
    const int h = blockIdx.z;
    const int w = 16 * h + wv;          // scan window 0..31
    const int k0 = 8 * w;               // scan offset
    const float* __restrict__ f0 = feat + (size_t)(4 * quad + 0) * HW;
    const float* __restrict__ f1 = feat + (size_t)(4 * quad + 1) * HW;
    const float* __restrict__ f2 = feat + (size_t)(4 * quad + 2) * HW;
    const float* __restrict__ f3 = feat + (size_t)(4 * quad + 3) * HW;
    float* __restrict__ o0 = out + (size_t)(4 * quad + 0) * (NA * NR);
    float* __restrict__ o1 = out + (size_t)(4 * quad + 1) * (NA * NR);
    float* __restrict__ o2 = out + (size_t)(4 * quad + 2) * (NA * NR);
    float* __restrict__ o3 = out + (size_t)(4 * quad + 3) * (NA * NR);

    // fast-axis indices owned by this lane (j = 0..3)
    const int fj0 = 2 * l;        // cols j=0,1
    const int fj2 = 2 * l + 128;  // cols j=2,3

    // ---- load persistent px tile: 8 scan x 4 fast x 4 img, f16 packed ----
    __half2 pxA[8][4], pxB[8][4];
    if (phase == 0) {
        // scan=y: row y=k0+k; fast=x at {2l,2l+1} and {2l+128,2l+129}
        #pragma unroll
        for (int k = 0; k < 8; ++k) {
            const int ro = (k0 + k) << 8;
            const float2 v0a = *(const float2*)(f0 + ro + fj0);
            const float2 v1a = *(const float2*)(f1 + ro + fj0);
            const float2 v2a = *(const float2*)(f2 + ro + fj0);
            const float2 v3a = *(const float2*)(f3 + ro + fj0);
            const float2 v0b = *(const float2*)(f0 + ro + fj2);
            const float2 v1b = *(const float2*)(f1 + ro + fj2);
            const float2 v2b = *(const float2*)(f2 + ro + fj2);
            const float2 v3b = *(const float2*)(f3 + ro + fj2);
            pxA[k][0] = __floats2half2_rn(v0a.x, v1a.x);
            pxB[k][0] = __floats2half2_rn(v2a.x, v3a.x);
            pxA[k][1] = __floats2half2_rn(v0a.y, v1a.y);
            pxB[k][1] = __floats2half2_rn(v2a.y, v3a.y);
            pxA[k][2] = __floats2half2_rn(v0b.x, v1b.x);
            pxB[k][2] = __floats2half2_rn(v2b.x, v3b.x);
            pxA[k][3] = __floats2half2_rn(v0b.y, v1b.y);
            pxB[k][3] = __floats2half2_rn(v2b.y, v3b.y);
        }
    } else {
        // scan=x: fast=y rows {2l,2l+1,2l+128,2l+129}; cols x=k0..k0+7
        #pragma unroll
        for (int j = 0; j < 4; ++j) {
            const int fr = (j < 2) ? (fj0 + j) : (fj2 + (j - 2));
            const int ro = fr << 8;
            const float4 q0 = *(const float4*)(f0 + ro + k0);
            const float4 q1 = *(const float4*)(f0 + ro + k0 + 4);
            const float4 r0 = *(const float4*)(f1 + ro + k0);
            const float4 r1 = *(const float4*)(f1 + ro + k0 + 4);
            const float4 s0 = *(const float4*)(f2 + ro + k0);
            const float4 s1 = *(const float4*)(f2 + ro + k0 + 4);
            const float4 t0 = *(const float4*)(f3 + ro + k0);
            const float4 t1 = *(const float4*)(f3 + ro + k0 + 4);
            pxA[0][j] = __floats2half2_rn(q0.x, r0.x);
            pxB[0][j] = __floats2half2_rn(s0.x, t0.x);
            pxA[1][j] = __floats2half2_rn(q0.y, r0.y);
            pxB[1][j] = __floats2half2_rn(s0.y, t0.y);
            pxA[2][j] = __floats2half2_rn(q0.z, r0.z);
            pxB[2][j] = __floats2half2_rn(s0.z, t0.z);
            pxA[3][j] = __floats2half2_rn(q0.w, r0.w);
            pxB[3][j] = __floats2half2_rn(s0.w, t0.w);
            pxA[4][j] = __floats2half2_rn(q1.x, r1.x);
            pxB[4][j] = __floats2half2_rn(s1.x, t1.x);
            pxA[5][j] = __floats2half2_rn(q1.y, r1.y);
            pxB[5][j] = __floats2half2_rn(s1.y, t1.y);
            pxA[6][j] = __floats2half2_rn(q1.z, r1.z);
            pxB[6][j] = __floats2half2_rn(s1.z, t1.z);
            pxA[7][j] = __floats2half2_rn(q1.w, r1.w);
            pxB[7][j] = __floats2half2_rn(s1.w, t1.w);
        }
    }

    const int nAng = phase ? 89 : 91;
    for (int cb = 0; cb < nAng; cb += CH) {
        const int cn = min(CH, nAng - cb);
        {   // zero rows (bit pattern 0 == f16 zero)
            float2* z = (float2*)rows;
            for (int i = t; i < 16 * CH * ROW_PAD; i += 1024)
                z[i] = make_float2(0.f, 0.f);
        }
        __syncthreads();

        for (int ai = 0; ai < cn; ++ai) {
            const int aidx = cb + ai;
            const int a = phase ? (46 + aidx) : (aidx <= 45 ? aidx : aidx + 89);
            const unsigned int* wrow = win + ((size_t)a * NWIN + w) * 256;
            const uint2 u0 = *(const uint2*)(wrow + fj0);   // cols 2l, 2l+1
            const uint2 u1 = *(const uint2*)(wrow + fj2);   // cols 2l+128, 2l+129
            uint4 wq; wq.x = u0.x; wq.y = u0.y; wq.z = u1.x; wq.w = u1.y;
            h4* __restrict__ rp = rows + (wv * CH + ai) * ROW_PAD;
            if (phase && a > 90) walk4h<-1>(wq, pxA, pxB, rp);
            else                 walk4h<+1>(wq, pxA, pxB, rp);
        }
        __syncthreads();

        // flush: sum the 16 wave copies in f32; lanes iterate rl contiguously
        // -> contiguous global atomics. Exactly-2 commutative contributions
        // per out element (the two scan-halves) -> deterministic.
        for (int i = t; i < cn * ROW_W; i += 1024) {
            const int al = i / ROW_W;
            const int rl = i - al * ROW_W;
            float s0 = 0.f, s1 = 0.f, s2 = 0.f, s3 = 0.f;
            #pragma unroll
            for (int c2 = 0; c2 < 16; ++c2) {
                const h4 v = rows[(c2 * CH + al) * ROW_PAD + rl];
                s0 += __low2float(v.a); s1 += __high2float(v.a);
                s2 += __low2float(v.b); s3 += __high2float(v.b);
            }
            const int aidx = cb + al;
            const int a = phase ? (46 + aidx) : (aidx <= 45 ? aidx : aidx + 89);
            const size_t o = (size_t)a * NR + (RBASE + rl);
            unsafeAtomicAdd(o0 + o, s0);
            unsafeAtomicAdd(o1 + o, s1);
            unsafeAtomicAdd(o2 + o, s2);
            unsafeAtomicAdd(o3 + o, s3);
        }
        __syncthreads();
    }
}

extern "C" void kernel_launch(void* const* d_in, const int* in_sizes, int n_in,
                              void* d_out, int out_size, void* d_ws, size_t ws_size,
                              hipStream_t stream) {
    const float* feat = (const float*)d_in[0];
    float* out = (float*)d_out;
    unsigned int* win = (unsigned int*)d_ws;

    const size_t win_bytes = (size_t)NA * NWIN * 256 * sizeof(unsigned int); // 5.9MB
    if (ws_size < win_bytes) return;

    const int n4 = out_size / 4;   // out_size = 512*180*723, divisible by 4
    hipLaunchKernelGGL(zero_out, dim3((n4 + 255) / 256), dim3(256), 0, stream,
                       (float4*)out, n4);
    hipLaunchKernelGGL(dht_win, dim3(NWIN, NA), dim3(256), 0, stream, win);
    hipLaunchKernelGGL(dht_main, dim3(NC / 4, 2, 2), dim3(1024), 0, stream,
                       feat, win, out);
}

// Round 19
// 818.246 us; speedup vs baseline: 2.1340x; 1.0475x over previous
//
#include <hip/hip_runtime.h>
#include <hip/hip_fp16.h>
#include <cmath>

// DHT: out[n,c,a,r] = sum over px (x,y) of feat[n,c,y,x],
//   r = rint((x-128)*cos(a deg) + (y-128)*sin(a deg)) + 361  (r in [180,542])
// feat[4,128,256,256] f32 -> out[4,128,180,723] f32.
//
// Locked-in findings:
//  R1-R4 (~31ms): LDS f32 atomicAdd ~per-lane serial -> never on hot path.
//  R5: wave-private rows + program-ordered DS RMW, race-free when lanes'
//    bins provably distinct PER INSTRUCTION. R10: exec-masked DS poison.
//  R8/9/13/14/15/17: SQ_LDS_BANK_CONFLICT = PORT-BYTE tax (halved exactly
//    with bytes, R17). R16: occupancy can't add port bandwidth.
//  R17 (846us, BEST): f16 accum, 4 img/b64 RMW. 22 cyc/RMW-pair vs ~14
//    port-need -> ~8 cyc latency-chain exposure.
//  R18 (FAILED): batching reads ahead of writes races ACROSS LANES (lane
//    spacing 1.4-2 bins < window span 7coef') -> reads must stay behind
//    overlapping writes in program order.
//  R14 (null): dual-angle interleave in ONE array -> compiler may-alias ->
//    serial chain anyway.
//  R19: dual-angle chains in TWO SEPARATE __shared__ objects (47KB each,
//    94KB total unchanged). Distinct objects -> provable no-alias ->
//    compiler batches rdA+rdB per latency window -> exposure ~halves.
//    Per-angle chain order unchanged -> bit-identical to R17.

#define NA 180
#define NR 723
#define HW 65536
#define NC 512
#define ROW_W 368       // bins rl = r-RBASE in [4,366]
#define ROW_PAD 368
#define RBASE 176
#define NWIN 32         // 8-px windows along the scan axis

__device__ __forceinline__ bool is_phase2(int a) { return a >= 46 && a <= 134; }

// 4 images packed per bin: .a = {img0,img1}, .b = {img2,img3}
struct __align__(8) h4 { __half2 a, b; };

// ---------------------------------------------------------------------------
// win[a][w][fast] u32 = base bin at scan=8w (bits 0..15), step bits 16..22.
// Phase-1 (a in [0,45]u[135,179]): fast=x, scan=y (step coef sin(a)>=0).
// Phase-2 (a in [46,134]):         fast=y, scan=x (step coef cos(a), sign
// flips at a=90). fp64 non-fused mul/add + rint bit-matches np.round
// (validated R1-R17).
// ---------------------------------------------------------------------------
__global__ __launch_bounds__(256) void dht_win(unsigned int* __restrict__ win) {
    const int lane = threadIdx.x;
    const int w = blockIdx.x;
    const int a = blockIdx.y;
    const double theta = (double)a * (M_PI / 180.0);
    const double c = cos(theta), s = sin(theta);
    const bool p2 = is_phase2(a);
    int prev = 0;
    unsigned int word = 0;
    #pragma unroll
    for (int i = 0; i < 8; ++i) {
        const int k = w * 8 + i;
        const int x = p2 ? k : lane;
        const int y = p2 ? lane : k;
        const double rho = __dadd_rn(__dmul_rn((double)(x - 128), c),
                                     __dmul_rn((double)(y - 128), s));
        int r = (int)rint(rho) + 361;
        r = min(max(r, 0), NR - 1);
        if (i == 0) word = (unsigned int)r;
        else if (r != prev) word |= (1u << (15 + i));
        prev = r;
    }
    win[((size_t)a * NWIN + w) * 256 + lane] = word;
}

__global__ __launch_bounds__(256) void zero_out(float4* __restrict__ o, int n4) {
    const int i = blockIdx.x * 256 + threadIdx.x;
    if (i < n4) o[i] = make_float4(0.f, 0.f, 0.f, 0.f);
}

// Single-angle walk (R17 form) for odd tail chunks. Per-visit read->add->
// write in strict program order; lanes 2 cols apart -> bins >= 1.414 apart
// per instruction -> race-free.
template <int SGN>
__device__ __forceinline__ void walk_one(const uint4 wq,
                                         const __half2 (&pxA)[8][4],
                                         const __half2 (&pxB)[8][4],
                                         h4* __restrict__ rp) {
    #pragma unroll
    for (int j = 0; j < 4; ++j) {
        const unsigned int wrd = (&wq.x)[j];
        int bin = (int)(wrd & 0xffffu) - RBASE;
        #pragma unroll
        for (int k = 0; k < 8; ++k) {
            if (k) bin += SGN * (int)((wrd >> (15 + k)) & 1u);
            h4 v = rp[bin];
            v.a = __hadd2(v.a, pxA[k][j]);
            v.b = __hadd2(v.b, pxB[k][j]);
            rp[bin] = v;
        }
    }
}

// Dual-angle walk: chain A (angle cb+0 -> rpA) and chain B (cb+1 -> rpB)
// interleaved per (j,k). rpA/rpB point into DISTINCT __shared__ objects ->
// compiler proves no-alias -> rdA+rdB issue together (one latency window
// covers two visits). Within each chain the per-bin add order is identical
// to R17 -> bit-identical results. Every DS op stays in program order.
template <int SGN0, int SGN1>
__device__ __forceinline__ void walk_dual(const uint4 wq0, const uint4 wq1,
                                          const __half2 (&pxA)[8][4],
                                          const __half2 (&pxB)[8][4],
                                          h4* __restrict__ rpA,
                                          h4* __restrict__ rpB) {
    #pragma unroll
    for (int j = 0; j < 4; ++j) {
        const unsigned int w0 = (&wq0.x)[j];
        const unsigned int w1 = (&wq1.x)[j];
        int b0 = (int)(w0 & 0xffffu) - RBASE;
        int b1 = (int)(w1 & 0xffffu) - RBASE;
        #pragma unroll
        for (int k = 0; k < 8; ++k) {
            if (k) {
                b0 += SGN0 * (int)((w0 >> (15 + k)) & 1u);
                b1 += SGN1 * (int)((w1 >> (15 + k)) & 1u);
            }
            h4 vA = rpA[b0];
            h4 vB = rpB[b1];
            vA.a = __hadd2(vA.a, pxA[k][j]);
            vA.b = __hadd2(vA.b, pxB[k][j]);
            vB.a = __hadd2(vB.a, pxA[k][j]);
            vB.b = __hadd2(vB.b, pxB[k][j]);
            rpA[b0] = vA;
            rpB[b1] = vB;
        }
    }
}

// ---------------------------------------------------------------------------
// Block = (image-quad, phase, scan-half). 1024 thr = 16 waves; wave wv owns
// scan window w = 16h+wv (8 scan lines); lane owns fast columns
// {2l, 2l+1, 2l+128, 2l+129} (j = 0..3). px as __half2 pairs, loaded +
// converted ONCE, reused across all angles of the phase.
// rowsA/rowsB[16 waves][ROW_PAD] h4 = 47.1 KB each -> 94 KB, 1 block/CU.
// ---------------------------------------------------------------------------
__global__ __launch_bounds__(1024, 4) void dht_main(const float* __restrict__ feat,
                                                    const unsigned int* __restrict__ win,
                                                    float* __restrict__ out) {
    __shared__ h4 rowsA[16 * ROW_PAD];   // angle cb+0 of each chunk
    __shared__ h4 rowsB[16 * ROW_PAD];   // angle cb+1 of each chunk
    const int t = threadIdx.x;
    const int wv = t >> 6;
    const int l = t & 63;
    const int quad = blockIdx.x;
    const int phase = blockIdx.y;
    const int h = blockIdx.z;
    const int w = 16 * h + wv;          // scan window 0..31
    const int k0 = 8 * w;               // scan offset
    const float* __restrict__ f0 = feat + (size_t)(4 * quad + 0) * HW;
    const float* __restrict__ f1 = feat + (size_t)(4 * quad + 1) * HW;
    const float* __restrict__ f2 = feat + (size_t)(4 * quad + 2) * HW;
    const float* __restrict__ f3 = feat + (size_t)(4 * quad + 3) * HW;
    float* __restrict__ o0 = out + (size_t)(4 * quad + 0) * (NA * NR);
    float* __restrict__ o1 = out + (size_t)(4 * quad + 1) * (NA * NR);
    float* __restrict__ o2 = out + (size_t)(4 * quad + 2) * (NA * NR);
    float* __restrict__ o3 = out + (size_t)(4 * quad + 3) * (NA * NR);

    // fast-axis indices owned by this lane (j = 0..3)
    const int fj0 = 2 * l;        // cols j=0,1
    const int fj2 = 2 * l + 128;  // cols j=2,3

    // ---- load persistent px tile: 8 scan x 4 fast x 4 img, f16 packed ----
    __half2 pxA[8][4], pxB[8][4];
    if (phase == 0) {
        // scan=y: row y=k0+k; fast=x at {2l,2l+1} and {2l+128,2l+129}
        #pragma unroll
        for (int k = 0; k < 8; ++k) {
            const int ro = (k0 + k) << 8;
            const float2 v0a = *(const float2*)(f0 + ro + fj0);
            const float2 v1a = *(const float2*)(f1 + ro + fj0);
            const float2 v2a = *(const float2*)(f2 + ro + fj0);
            const float2 v3a = *(const float2*)(f3 + ro + fj0);
            const float2 v0b = *(const float2*)(f0 + ro + fj2);
            const float2 v1b = *(const float2*)(f1 + ro + fj2);
            const float2 v2b = *(const float2*)(f2 + ro + fj2);
            const float2 v3b = *(const float2*)(f3 + ro + fj2);
            pxA[k][0] = __floats2half2_rn(v0a.x, v1a.x);
            pxB[k][0] = __floats2half2_rn(v2a.x, v3a.x);
            pxA[k][1] = __floats2half2_rn(v0a.y, v1a.y);
            pxB[k][1] = __floats2half2_rn(v2a.y, v3a.y);
            pxA[k][2] = __floats2half2_rn(v0b.x, v1b.x);
            pxB[k][2] = __floats2half2_rn(v2b.x, v3b.x);
            pxA[k][3] = __floats2half2_rn(v0b.y, v1b.y);
            pxB[k][3] = __floats2half2_rn(v2b.y, v3b.y);
        }
    } else {
        // scan=x: fast=y rows {2l,2l+1,2l+128,2l+129}; cols x=k0..k0+7
        #pragma unroll
        for (int j = 0; j < 4; ++j) {
            const int fr = (j < 2) ? (fj0 + j) : (fj2 + (j - 2));
            const int ro = fr << 8;
            const float4 q0 = *(const float4*)(f0 + ro + k0);
            const float4 q1 = *(const float4*)(f0 + ro + k0 + 4);
            const float4 r0 = *(const float4*)(f1 + ro + k0);
            const float4 r1 = *(const float4*)(f1 + ro + k0 + 4);
            const float4 s0 = *(const float4*)(f2 + ro + k0);
            const float4 s1 = *(const float4*)(f2 + ro + k0 + 4);
            const float4 t0 = *(const float4*)(f3 + ro + k0);
            const float4 t1 = *(const float4*)(f3 + ro + k0 + 4);
            pxA[0][j] = __floats2half2_rn(q0.x, r0.x);
            pxB[0][j] = __floats2half2_rn(s0.x, t0.x);
            pxA[1][j] = __floats2half2_rn(q0.y, r0.y);
            pxB[1][j] = __floats2half2_rn(s0.y, t0.y);
            pxA[2][j] = __floats2half2_rn(q0.z, r0.z);
            pxB[2][j] = __floats2half2_rn(s0.z, t0.z);
            pxA[3][j] = __floats2half2_rn(q0.w, r0.w);
            pxB[3][j] = __floats2half2_rn(s0.w, t0.w);
            pxA[4][j] = __floats2half2_rn(q1.x, r1.x);
            pxB[4][j] = __floats2half2_rn(s1.x, t1.x);
            pxA[5][j] = __floats2half2_rn(q1.y, r1.y);
            pxB[5][j] = __floats2half2_rn(s1.y, t1.y);
            pxA[6][j] = __floats2half2_rn(q1.z, r1.z);
            pxB[6][j] = __floats2half2_rn(s1.z, t1.z);
            pxA[7][j] = __floats2half2_rn(q1.w, r1.w);
            pxB[7][j] = __floats2half2_rn(s1.w, t1.w);
        }
    }

    const int nAng = phase ? 89 : 91;   // both odd: pairs + one tail angle
    for (int cb = 0; cb < nAng; cb += 2) {
        const int cn = min(2, nAng - cb);
        {   // zero both copies (bit pattern 0 == f16 zero)
            float2* zA = (float2*)rowsA;
            float2* zB = (float2*)rowsB;
            for (int i = t; i < 16 * ROW_PAD; i += 1024) {
                zA[i] = make_float2(0.f, 0.f);
                zB[i] = make_float2(0.f, 0.f);
            }
        }
        __syncthreads();

        const int a0 = phase ? (46 + cb) : (cb <= 45 ? cb : cb + 89);
        h4* __restrict__ rpA = rowsA + wv * ROW_PAD;
        if (cn == 2) {
            const int ax1 = cb + 1;
            const int a1 = phase ? (46 + ax1) : (ax1 <= 45 ? ax1 : ax1 + 89);
            const unsigned int* wr0 = win + ((size_t)a0 * NWIN + w) * 256;
            const unsigned int* wr1 = win + ((size_t)a1 * NWIN + w) * 256;
            const uint2 p00 = *(const uint2*)(wr0 + fj0);
            const uint2 p01 = *(const uint2*)(wr0 + fj2);
            const uint2 p10 = *(const uint2*)(wr1 + fj0);
            const uint2 p11 = *(const uint2*)(wr1 + fj2);
            uint4 wq0; wq0.x = p00.x; wq0.y = p00.y; wq0.z = p01.x; wq0.w = p01.y;
            uint4 wq1; wq1.x = p10.x; wq1.y = p10.y; wq1.z = p11.x; wq1.w = p11.y;
            h4* __restrict__ rpB = rowsB + wv * ROW_PAD;
            if (!phase || a1 <= 90)
                walk_dual<+1, +1>(wq0, wq1, pxA, pxB, rpA, rpB);
            else if (a0 > 90)
                walk_dual<-1, -1>(wq0, wq1, pxA, pxB, rpA, rpB);
            else
                walk_dual<+1, -1>(wq0, wq1, pxA, pxB, rpA, rpB);
        } else {
            const unsigned int* wr0 = win + ((size_t)a0 * NWIN + w) * 256;
            const uint2 p00 = *(const uint2*)(wr0 + fj0);
            const uint2 p01 = *(const uint2*)(wr0 + fj2);
            uint4 wq0; wq0.x = p00.x; wq0.y = p00.y; wq0.z = p01.x; wq0.w = p01.y;
            if (phase && a0 > 90) walk_one<-1>(wq0, pxA, pxB, rpA);
            else                  walk_one<+1>(wq0, pxA, pxB, rpA);
        }
        __syncthreads();

        // flush: sum 16 wave copies in f32 (al=0 from rowsA, al=1 rowsB);
        // lanes iterate rl contiguously -> contiguous global atomics.
        // Exactly-2 commutative contributions per out element -> deterministic.
        for (int i = t; i < cn * ROW_W; i += 1024) {
            const int al = i / ROW_W;
            const int rl = i - al * ROW_W;
            const h4* __restrict__ src = al ? rowsB : rowsA;
            float s0 = 0.f, s1 = 0.f, s2 = 0.f, s3 = 0.f;
            #pragma unroll
            for (int c2 = 0; c2 < 16; ++c2) {
                const h4 v = src[c2 * ROW_PAD + rl];
                s0 += __low2float(v.a); s1 += __high2float(v.a);
                s2 += __low2float(v.b); s3 += __high2float(v.b);
            }
            const int aidx = cb + al;
            const int a = phase ? (46 + aidx) : (aidx <= 45 ? aidx : aidx + 89);
            const size_t o = (size_t)a * NR + (RBASE + rl);
            unsafeAtomicAdd(o0 + o, s0);
            unsafeAtomicAdd(o1 + o, s1);
            unsafeAtomicAdd(o2 + o, s2);
            unsafeAtomicAdd(o3 + o, s3);
        }
        __syncthreads();
    }
}

extern "C" void kernel_launch(void* const* d_in, const int* in_sizes, int n_in,
                              void* d_out, int out_size, void* d_ws, size_t ws_size,
                              hipStream_t stream) {
    const float* feat = (const float*)d_in[0];
    float* out = (float*)d_out;
    unsigned int* win = (unsigned int*)d_ws;

    const size_t win_bytes = (size_t)NA * NWIN * 256 * sizeof(unsigned int); // 5.9MB
    if (ws_size < win_bytes) return;

    const int n4 = out_size / 4;   // out_size = 512*180*723, divisible by 4
    hipLaunchKernelGGL(zero_out, dim3((n4 + 255) / 256), dim3(256), 0, stream,
                       (float4*)out, n4);
    hipLaunchKernelGGL(dht_win, dim3(NWIN, NA), dim3(256), 0, stream, win);
    hipLaunchKernelGGL(dht_main, dim3(NC / 4, 2, 2), dim3(1024), 0, stream,
                       feat, win, out);
}